// Round 7
// baseline (62.998 us; speedup 1.0000x reference)
//
#include <hip/hip_runtime.h>
#include <hip/hip_bf16.h>
#include <stdint.h>

constexpr int NUM_NODES = 120000;
constexpr int Tn = 10;
constexpr int Bb = 64, Rr = 4, Nn = 64, Cc = 64, Ii = 64;
constexpr int RSTR  = 147456;   // per-relation Wf stride (bf16 elems)
constexpr int OFF0  = 0;        // L0 w1   [tap2][ct4][ks4][lane64][8]
constexpr int OFF1  = 16384;    // L0 down [ct4][ks4][lane64][8]
constexpr int OFF2  = 24576;    // L0 w2   [tap2][ct4][ks2][lane64][8]
constexpr int OFFL0 = 32768;    // levels  14 x [tap2][ct4][ks2][lane64][8]

// LDS byte offsets. X (160 cols x 256B) dead after pass2; H-chain aliases it.
constexpr int OFF_X  = 0;        // 40960
constexpr int OFF_H0 = 0;        // 5 slots  (10240)
constexpr int OFF_H1 = 10240;    // 3 slots  (6144)
constexpr int OFF_H2 = 16384;    // 2 slots  (4096)
constexpr int OFF_H3 = 20480;    // 1 slot   (2048); H4/H5/H6 follow at +2048 each
constexpr int OFF_Y  = 40960;    // up to 10 slots (20480)
constexpr int ZOFF   = 61440;    // 256B zero block
constexpr int SMEMB  = 61696;

typedef __attribute__((ext_vector_type(8))) short bf16x8;
typedef __attribute__((ext_vector_type(4))) float f32x4;
typedef __attribute__((ext_vector_type(4))) short s16x4;

__device__ __forceinline__ short f2bf(float f) {
  __hip_bfloat16 h = __float2bfloat16(f);
  return *reinterpret_cast<short*>(&h);
}
__device__ __forceinline__ float bf2f(short s) {
  union { unsigned int u; float f; } x;
  x.u = ((unsigned int)(unsigned short)s) << 16;
  return x.f;
}

// ---------------------------------------------------------------------------
// Bake weights into per-lane MFMA A-fragments (bf16). (verified rounds 3-6)
// ---------------------------------------------------------------------------
extern "C" __global__ void prep_kernel(const float* __restrict__ w1_0,
                                       const float* __restrict__ w2_0,
                                       const float* __restrict__ down_w,
                                       const float* __restrict__ w1s,
                                       const float* __restrict__ w2s,
                                       short* __restrict__ Wf) {
  int i0 = blockIdx.x * blockDim.x + threadIdx.x;
  int stride = gridDim.x * blockDim.x;
  for (int e = i0; e < Rr * RSTR; e += stride) {
    int r = e / RSTR, q = e - r * RSTR;
    float v;
    if (q < 16384) {
      int j = q & 7, lane = (q >> 3) & 63, ks = (q >> 9) & 3, ct = (q >> 11) & 3, tap = (q >> 13) & 1;
      int cout = ct * 16 + (lane & 15), cin = ks * 32 + (lane >> 4) * 8 + j;
      v = w1_0[((r * 64 + cout) * 128 + cin) * 2 + tap];
    } else if (q < 24576) {
      int q2 = q - 16384;
      int j = q2 & 7, lane = (q2 >> 3) & 63, ks = (q2 >> 9) & 3, ct = (q2 >> 11) & 3;
      int cout = ct * 16 + (lane & 15), cin = ks * 32 + (lane >> 4) * 8 + j;
      v = down_w[(r * 64 + cout) * 128 + cin];
    } else if (q < 32768) {
      int q2 = q - 24576;
      int j = q2 & 7, lane = (q2 >> 3) & 63, ks = (q2 >> 9) & 1, ct = (q2 >> 10) & 3, tap = (q2 >> 12) & 1;
      int cout = ct * 16 + (lane & 15), cin = ks * 32 + (lane >> 4) * 8 + j;
      v = w2_0[((r * 64 + cout) * 64 + cin) * 2 + tap];
    } else {
      int q2 = q - 32768;
      int lc = q2 >> 13;
      int l = lc >> 1, jw = lc & 1;
      int q3 = q2 & 8191;
      int j = q3 & 7, lane = (q3 >> 3) & 63, ks = (q3 >> 9) & 1, ct = (q3 >> 10) & 3, tap = (q3 >> 12) & 1;
      int cout = ct * 16 + (lane & 15), cin = ks * 32 + (lane >> 4) * 8 + j;
      const float* src = jw ? w2s : w1s;
      v = src[(((r * 7 + l) * 64 + cout) * 64 + cin) * 2 + tap];
    }
    Wf[e] = f2bf(v);
  }
}

// ---------------------------------------------------------------------------
// Sparse-slot conv pass. col = slot*16 + seq (16 seqs); tile == slot.
// T1/T0: per-tile input-slot maps (-1 => zero block).
// ---------------------------------------------------------------------------
template <int KSN, int NMT, int NTAP, int ROWB>
__device__ __forceinline__ void conv_sp(const char* __restrict__ sm, int srcOff,
                                        const short* __restrict__ wf1,
                                        const short* __restrict__ wf0,
                                        const float* __restrict__ bias,
                                        const int (&T1)[NMT], const int (&T0)[NMT],
                                        int lane, int ct, f32x4 (&acc)[NMT]) {
  const int c16 = (lane >> 4) * 16;
  const int sw = (lane & 7) << 4;
  const int cm = lane & 15;
  float bv[4];
#pragma unroll
  for (int g = 0; g < 4; ++g) bv[g] = bias[ct * 16 + (lane >> 4) * 4 + g];
#pragma unroll
  for (int mt = 0; mt < NMT; ++mt) acc[mt] = (f32x4){bv[0], bv[1], bv[2], bv[3]};
  bf16x8 af1[KSN], af0[KSN];
#pragma unroll
  for (int ks = 0; ks < KSN; ++ks)
    af1[ks] = *(const bf16x8*)(wf1 + ((ct * KSN + ks) * 64 + lane) * 8);
  if (NTAP == 2) {
#pragma unroll
    for (int ks = 0; ks < KSN; ++ks)
      af0[ks] = *(const bf16x8*)(wf0 + ((ct * KSN + ks) * 64 + lane) * 8);
  }
#pragma unroll
  for (int mt = 0; mt < NMT; ++mt) {
    int s1 = T1[mt];
    const char* p1 = sm + ((s1 < 0) ? ZOFF : srcOff + (s1 * 16 + cm) * ROWB);
#pragma unroll
    for (int ks = 0; ks < KSN; ++ks) {
      bf16x8 b = *(const bf16x8*)(p1 + ((ks * 64 + c16) ^ sw));
      acc[mt] = __builtin_amdgcn_mfma_f32_16x16x32_bf16(af1[ks], b, acc[mt], 0, 0, 0);
    }
    if (NTAP == 2) {
      int s0 = T0[mt];
      const char* p0 = sm + ((s0 < 0) ? ZOFF : srcOff + (s0 * 16 + cm) * ROWB);
#pragma unroll
      for (int ks = 0; ks < KSN; ++ks) {
        bf16x8 b = *(const bf16x8*)(p0 + ((ks * 64 + c16) ^ sw));
        acc[mt] = __builtin_amdgcn_mfma_f32_16x16x32_bf16(af0[ks], b, acc[mt], 0, 0, 0);
      }
    }
  }
}

template <int NMT>
__device__ __forceinline__ void store_sp(char* __restrict__ sm, int dstOff, int s0,
                                         int lane, int ct, const f32x4 (&v)[NMT]) {
  const int co = ct * 32 + (lane >> 4) * 8;
  const int sw = (lane & 7) << 4;
#pragma unroll
  for (int mt = 0; mt < NMT; ++mt) {
    int oc = (s0 + mt) * 16 + (lane & 15);
    s16x4 p;
#pragma unroll
    for (int g = 0; g < 4; ++g) p[g] = f2bf(v[mt][g]);
    *(s16x4*)(sm + dstOff + oc * 128 + (co ^ sw)) = p;
  }
}

#define RELU_ALL(A, N)                                        \
  _Pragma("unroll") for (int _t = 0; _t < N; ++_t)            \
      _Pragma("unroll") for (int _g = 0; _g < 4; ++_g)        \
          A[_t][_g] = fmaxf(A[_t][_g], 0.f);

// residual: h = relu(relu(acc) + H_prev(bf16 LDS))
template <int NMT>
__device__ __forceinline__ void resid_sp(const char* __restrict__ sm, int prevOff,
                                         const int (&R)[NMT], int lane, int ct,
                                         f32x4 (&a)[NMT]) {
  const int co = ct * 32 + (lane >> 4) * 8;
  const int sw = (lane & 7) << 4;
  const int cm = lane & 15;
#pragma unroll
  for (int mt = 0; mt < NMT; ++mt) {
    const char* p = sm + prevOff + (R[mt] * 16 + cm) * 128;
    s16x4 q = *(const s16x4*)(p + (co ^ sw));
#pragma unroll
    for (int g = 0; g < 4; ++g)
      a[mt][g] = fmaxf(fmaxf(a[mt][g], 0.f) + bf2f(q[g]), 0.f);
  }
}

// ---------------------------------------------------------------------------
// Main: 16 valid seqs per block, 512 thr = 8 waves (4 cout-tiles x 2 halves).
// Grid = r(4) x b(64) x chunk(4) = 1024 blocks.
// ---------------------------------------------------------------------------
extern "C" __global__ void __launch_bounds__(512, 4)
tcn_mfma(const float* __restrict__ emb, const int* __restrict__ align_,
         const int* __restrict__ nidx, const int* __restrict__ nmask,
         const float* __restrict__ b1_0, const float* __restrict__ b2_0,
         const float* __restrict__ down_b, const float* __restrict__ b1s,
         const float* __restrict__ b2s, const short* __restrict__ Wf,
         float* __restrict__ P) {
  __shared__ char sm[SMEMB];
  __shared__ int rowid[160];
  __shared__ float mkv[16];
  __shared__ int mapg[16];
  __shared__ int totv;

  const int tid = threadIdx.x;
  const int lane = tid & 63, wave = tid >> 6;
  const int ct = wave & 3, half = wave >> 2;
  const int blk = blockIdx.x;
  const int r = blk >> 8;
  const int b = (blk >> 2) & 63, chunk = blk & 3;

  // ---- ballot compaction (wave 0) ----
  if (tid < 64) {
    int n = tid;
    int msk = nmask[(b * Rr + r) * Nn + n];
    unsigned long long bal = __ballot(msk != 0);
    if (tid < 16) mapg[tid] = -1;
    if (tid == 0) totv = (int)__popcll(bal);
    int rank = (int)__popcll(bal & ((1ull << n) - 1ull));
    if (msk != 0 && rank >= chunk * 16 && rank < chunk * 16 + 16)
      mapg[rank - chunk * 16] = n;
  }
  if (tid >= 448 && tid < 480) *(uint64_t*)(sm + ZOFF + (tid - 448) * 8) = 0;
  __syncthreads();
  if (chunk * 16 >= totv) {
    if (tid < 64) P[((r * Bb + b) * 4 + chunk) * 64 + tid] = 0.f;
    return;
  }

  // col = t*16 + seq
  if (tid < 160) {
    int t = tid >> 4, seq = tid & 15;
    int n2 = mapg[seq];
    int s = -1;
    if (n2 >= 0) {
      int ent = nidx[(b * Rr + r) * Nn + n2];
      s = align_[ent * Tn + t];
    }
    rowid[tid] = (n2 >= 0 && s >= 0) ? s : -1;
    if (t == 0) mkv[seq] = (n2 >= 0) ? 1.0f : 0.0f;
  }
  __syncthreads();

  // gather: 160 cols x 128 d, f32 -> bf16, swizzled LDS write
#pragma unroll
  for (int it = 0; it < 10; ++it) {
    int idx = tid + it * 512;
    int col = idx >> 5, d4 = idx & 31;
    int row = rowid[col];
    int t = col >> 4;
    s16x4 p = {0, 0, 0, 0};
    if (row >= 0) {
      const float4 v = *(const float4*)(emb + ((size_t)t * NUM_NODES + row) * 128 + d4 * 4);
      p[0] = f2bf(v.x); p[1] = f2bf(v.y); p[2] = f2bf(v.z); p[3] = f2bf(v.w);
    }
    *(s16x4*)(sm + OFF_X + col * 256 + ((d4 * 8) ^ ((col & 7) << 4))) = p;
  }
  __syncthreads();

  const short* wr = Wf + r * RSTR;

  // ---- pass1: Y0 = relu(conv1_0(X)), 10 slots ----
  {
    static constexpr int T1a[5] = {0, 1, 2, 3, 4}, T0a[5] = {-1, 0, 1, 2, 3};
    static constexpr int T1b[5] = {5, 6, 7, 8, 9}, T0b[5] = {4, 5, 6, 7, 8};
    f32x4 a[5];
    conv_sp<4, 5, 2, 256>(sm, OFF_X, wr + OFF0 + 8192, wr + OFF0, b1_0 + r * 64,
                          half ? T1b : T1a, half ? T0b : T0a, lane, ct, a);
    RELU_ALL(a, 5)
    store_sp<5>(sm, OFF_Y, half ? 5 : 0, lane, ct, a);
  }
  // ---- pass2: down(X) at odd t {1,3,5}/{5,7,9}, regs ----
  f32x4 accD[3];
  {
    static constexpr int TDa[3] = {1, 3, 5}, TDb[3] = {5, 7, 9};
    conv_sp<4, 3, 1, 256>(sm, OFF_X, wr + OFF1, wr + OFF1, down_b + r * 64,
                          half ? TDb : TDa, half ? TDb : TDa, lane, ct, accD);
  }
  __syncthreads();
  // ---- pass3: H0 = relu(relu(conv2_0(Y0)) + down), slots t={1,3,5,7,9} ----
  {
    static constexpr int T1a[3] = {1, 3, 5}, T0a[3] = {0, 2, 4};
    static constexpr int T1b[3] = {5, 7, 9}, T0b[3] = {4, 6, 8};
    f32x4 a[3];
    conv_sp<2, 3, 2, 128>(sm, OFF_Y, wr + OFF2 + 4096, wr + OFF2, b2_0 + r * 64,
                          half ? T1b : T1a, half ? T0b : T0a, lane, ct, a);
#pragma unroll
    for (int mt = 0; mt < 3; ++mt)
#pragma unroll
      for (int g = 0; g < 4; ++g)
        a[mt][g] = fmaxf(fmaxf(a[mt][g], 0.f) + accD[mt][g], 0.f);
    store_sp<3>(sm, OFF_H0, half ? 2 : 0, lane, ct, a);
  }
  __syncthreads();
  // ---- L1a (d=2): Y at H0 slots {0..4} ----
  {
    static constexpr int T1a[3] = {0, 1, 2}, T0a[3] = {-1, 0, 1};
    static constexpr int T1b[3] = {2, 3, 4}, T0b[3] = {1, 2, 3};
    const short* wl = wr + OFFL0;
    f32x4 a[3];
    conv_sp<2, 3, 2, 128>(sm, OFF_H0, wl + 4096, wl, b1s + (r * 7 + 0) * 64,
                          half ? T1b : T1a, half ? T0b : T0a, lane, ct, a);
    RELU_ALL(a, 3)
    store_sp<3>(sm, OFF_Y, half ? 2 : 0, lane, ct, a);
  }
  __syncthreads();
  // ---- L1b: H1 at t={1,5,9} ----
  {
    static constexpr int T1a[2] = {0, 2}, T0a[2] = {-1, 1}, Ra[2] = {0, 2};
    static constexpr int T1b[2] = {2, 4}, T0b[2] = {1, 3}, Rb[2] = {2, 4};
    const short* wl = wr + OFFL0 + 8192;
    f32x4 a[2];
    conv_sp<2, 2, 2, 128>(sm, OFF_Y, wl + 4096, wl, b2s + (r * 7 + 0) * 64,
                          half ? T1b : T1a, half ? T0b : T0a, lane, ct, a);
    resid_sp<2>(sm, OFF_H0, half ? Rb : Ra, lane, ct, a);
    store_sp<2>(sm, OFF_H1, half ? 1 : 0, lane, ct, a);
  }
  __syncthreads();
  // ---- L2a (d=4): Y at t={1,5,9} ----
  {
    static constexpr int T1a[2] = {0, 1}, T0a[2] = {-1, 0};
    static constexpr int T1b[2] = {1, 2}, T0b[2] = {0, 1};
    const short* wl = wr + OFFL0 + 16384;
    f32x4 a[2];
    conv_sp<2, 2, 2, 128>(sm, OFF_H1, wl + 4096, wl, b1s + (r * 7 + 1) * 64,
                          half ? T1b : T1a, half ? T0b : T0a, lane, ct, a);
    RELU_ALL(a, 2)
    store_sp<2>(sm, OFF_Y, half ? 1 : 0, lane, ct, a);
  }
  __syncthreads();
  // ---- L2b: H2 at t={1,9} ----
  {
    static constexpr int T1a[1] = {0}, T0a[1] = {-1}, Ra[1] = {0};
    static constexpr int T1b[1] = {2}, T0b[1] = {1}, Rb[1] = {2};
    const short* wl = wr + OFFL0 + 16384 + 8192;
    f32x4 a[1];
    conv_sp<2, 1, 2, 128>(sm, OFF_Y, wl + 4096, wl, b2s + (r * 7 + 1) * 64,
                          half ? T1b : T1a, half ? T0b : T0a, lane, ct, a);
    resid_sp<1>(sm, OFF_H1, half ? Rb : Ra, lane, ct, a);
    store_sp<1>(sm, OFF_H2, half ? 1 : 0, lane, ct, a);
  }
  __syncthreads();
  // ---- L3a (d=8): Y at t={1,9} ----
  {
    static constexpr int T1a[1] = {0}, T0a[1] = {-1};
    static constexpr int T1b[1] = {1}, T0b[1] = {0};
    const short* wl = wr + OFFL0 + 32768;
    f32x4 a[1];
    conv_sp<2, 1, 2, 128>(sm, OFF_H2, wl + 4096, wl, b1s + (r * 7 + 2) * 64,
                          half ? T1b : T1a, half ? T0b : T0a, lane, ct, a);
    RELU_ALL(a, 1)
    store_sp<1>(sm, OFF_Y, half ? 1 : 0, lane, ct, a);
  }
  __syncthreads();
  // ---- L3b: H3 at t={9} (dup across halves, identical bytes) ----
  {
    static constexpr int T1c[1] = {1}, T0c[1] = {0}, Rc[1] = {1};
    const short* wl = wr + OFFL0 + 32768 + 8192;
    f32x4 a[1];
    conv_sp<2, 1, 2, 128>(sm, OFF_Y, wl + 4096, wl, b2s + (r * 7 + 2) * 64,
                          T1c, T0c, lane, ct, a);
    resid_sp<1>(sm, OFF_H2, Rc, lane, ct, a);
    store_sp<1>(sm, OFF_H3, 0, lane, ct, a);
  }
  __syncthreads();

  // ---- levels 4..7: wave 0 only, barrier-free (wave-local LDS ordering) ----
  if (wave != 0) return;

  f32x4 hfin[4];
  static constexpr int TA[1] = {0};
#pragma unroll 1
  for (int li = 0; li < 4; ++li) {
    const short* base = wr + OFFL0 + (3 + li) * 16384;
    const int prevOff = OFF_H3 + li * 2048;
#pragma unroll
    for (int c2 = 0; c2 < 4; ++c2) {
      f32x4 a[1];
      conv_sp<2, 1, 1, 128>(sm, prevOff, base + 4096, base + 4096,
                            b1s + (r * 7 + 3 + li) * 64, TA, TA, lane, c2, a);
      RELU_ALL(a, 1)
      store_sp<1>(sm, OFF_Y, 0, lane, c2, a);
    }
    __builtin_amdgcn_s_waitcnt(0);
    __builtin_amdgcn_sched_barrier(0);
#pragma unroll
    for (int c2 = 0; c2 < 4; ++c2) {
      f32x4 a[1];
      conv_sp<2, 1, 1, 128>(sm, OFF_Y, base + 8192 + 4096, base + 8192 + 4096,
                            b2s + (r * 7 + 3 + li) * 64, TA, TA, lane, c2, a);
      resid_sp<1>(sm, prevOff, TA, lane, c2, a);
      if (li < 3) store_sp<1>(sm, prevOff + 2048, 0, lane, c2, a);
      hfin[c2] = a[0];
    }
    __builtin_amdgcn_s_waitcnt(0);
    __builtin_amdgcn_sched_barrier(0);
  }

  // ---- epilogue: mask + reduce over 16 seqs (lane&15), write P ----
  float mk = mkv[lane & 15];
#pragma unroll
  for (int c2 = 0; c2 < 4; ++c2) {
    float s0 = hfin[c2][0] * mk, s1 = hfin[c2][1] * mk;
    float s2 = hfin[c2][2] * mk, s3 = hfin[c2][3] * mk;
#pragma unroll
    for (int m2 = 1; m2 <= 8; m2 <<= 1) {
      s0 += __shfl_xor(s0, m2);
      s1 += __shfl_xor(s1, m2);
      s2 += __shfl_xor(s2, m2);
      s3 += __shfl_xor(s3, m2);
    }
    if ((lane & 15) == 0) {
      int base = ((r * Bb + b) * 4 + chunk) * 64 + c2 * 16 + (lane >> 4) * 4;
      P[base + 0] = s0;
      P[base + 1] = s1;
      P[base + 2] = s2;
      P[base + 3] = s3;
    }
  }
}

// ---------------------------------------------------------------------------
// out[b][i] = sum_r sum_c (sum_p P[r][b][p][c]) * rel_w[r][c][i]
// ---------------------------------------------------------------------------
extern "C" __global__ void reduce_kernel(const float* __restrict__ P,
                                         const float* __restrict__ rel_w,
                                         float* __restrict__ out) {
  __shared__ float Sl[Rr * Cc];
  int b = blockIdx.x, i = threadIdx.x;
  for (int idx = i; idx < Rr * Cc; idx += 64) {
    int rr = idx >> 6, cc = idx & 63;
    float s = 0.f;
    for (int p = 0; p < 4; ++p) s += P[((rr * Bb + b) * 4 + p) * 64 + cc];
    Sl[idx] = s;
  }
  __syncthreads();
  float acc = 0.f;
  for (int r = 0; r < Rr; ++r)
#pragma unroll
    for (int cc = 0; cc < 64; ++cc)
      acc += Sl[r * Cc + cc] * rel_w[(r * Cc + cc) * Ii + i];
  out[b * Ii + i] = acc;
}

// ---------------------------------------------------------------------------
extern "C" void kernel_launch(void* const* d_in, const int* in_sizes, int n_in,
                              void* d_out, int out_size, void* d_ws, size_t ws_size,
                              hipStream_t stream) {
  const float* emb    = (const float*)d_in[0];
  const float* w1_0   = (const float*)d_in[1];
  const float* b1_0   = (const float*)d_in[2];
  const float* w2_0   = (const float*)d_in[3];
  const float* b2_0   = (const float*)d_in[4];
  const float* down_w = (const float*)d_in[5];
  const float* down_b = (const float*)d_in[6];
  const float* w1s    = (const float*)d_in[7];
  const float* b1s    = (const float*)d_in[8];
  const float* w2s    = (const float*)d_in[9];
  const float* b2s    = (const float*)d_in[10];
  const float* rel_w  = (const float*)d_in[11];
  const int* align_   = (const int*)d_in[12];
  const int* nidx     = (const int*)d_in[13];
  const int* nmask    = (const int*)d_in[14];

  float* P  = (float*)d_ws;                       // 4*64*4*64 f32 = 256 KB
  short* Wf = (short*)((char*)d_ws + 524288);     // 589824 bf16 = 1.15 MB

  prep_kernel<<<768, 256, 0, stream>>>(w1_0, w2_0, down_w, w1s, w2s, Wf);
  tcn_mfma<<<1024, 512, 0, stream>>>(emb, align_, nidx, nmask, b1_0, b2_0, down_b,
                                     b1s, b2s, Wf, P);
  reduce_kernel<<<Bb, Cc, 0, stream>>>(P, rel_w, (float*)d_out);
}